// Round 3
// baseline (8544.551 us; speedup 1.0000x reference)
//
#include <hip/hip_runtime.h>

// ---------------------------------------------------------------------------
// BiLSTM-CRF forward loss on MI355X (gfx950).
// Decomposition:
//   K0 prep:   f32 -> bf16 weight swizzle into per-lane MFMA B-fragment order.
//   K1 lstm:   16 WGs (2 dirs x 8 batch-tiles of 16 rows). Each WG runs all
//              512 recurrence steps locally (no inter-WG sync): gates via
//              mfma_f32_16x16x32_bf16, h/c in LDS/regs, fused emissions GEMM.
//   K2 crf:    128 blocks (1 wave per batch element): gold score + forward
//              algorithm (logsumexp via exp(trans) matvec).
//   K3 final:  reduce 128 partials -> |sum| scalar, f32 output.
// Contract notes (established rounds 0-2):
//   - output dtype: float32 (4-byte store).
//   - mask input: int32 (harness converts bool -> int), NOT bytes.
// Workspace layout (bytes):
//   [0)            em: [2][128][512][20] f32 (fwd, bwd emission parts, no bout)
//   [10485760)     whh_sw: 2 x 64nt x 8kt x 64lane x 8 bf16
//   [11534336)     wih_sw: 2 x 64nt x 4kt x 64lane x 8 bf16 (K=100 pad 128)
//   [12058624)     wout_sw: 2 x 2nt x 8kt x 64lane x 8 bf16 (T=20 pad 32)
//   [12091392)     bias: [2][1024] f32 (bih+bhh)
//   [12099584)     partial: [128] f32
// Total ~12.1 MB.
// ---------------------------------------------------------------------------

typedef short s16x8 __attribute__((ext_vector_type(8)));
typedef float f32x4 __attribute__((ext_vector_type(4)));

#define MFMA16(a, b, c) __builtin_amdgcn_mfma_f32_16x16x32_bf16((a), (b), (c), 0, 0, 0)

__device__ __forceinline__ unsigned short f2bf(float x) {
  unsigned u = __float_as_uint(x);
  u += 0x7FFFu + ((u >> 16) & 1u);  // round-to-nearest-even
  return (unsigned short)(u >> 16);
}
__device__ __forceinline__ float bf2f(unsigned short h) {
  return __uint_as_float(((unsigned)h) << 16);
}
__device__ __forceinline__ float sigm(float x) {
  return __builtin_amdgcn_rcpf(1.f + __expf(-x));
}
__device__ __forceinline__ float tanh_(float x) {
  float e = __expf(2.f * x);
  return (e - 1.f) * __builtin_amdgcn_rcpf(e + 1.f);
}

// ---------------------------------------------------------------------------
// K0: weight prep (convert + swizzle into MFMA fragment order).
// B-fragment for (ntile n, ktile kt): lane l, elem e <- W[n*16+(l&15)][kt*32+(l>>4)*8+e]
// ---------------------------------------------------------------------------
__global__ __launch_bounds__(256) void prep_kernel(
    const float* __restrict__ Whh_f, const float* __restrict__ Whh_b,
    const float* __restrict__ Wih_f, const float* __restrict__ Wih_b,
    const float* __restrict__ Wout,
    const float* __restrict__ bih_f, const float* __restrict__ bhh_f,
    const float* __restrict__ bih_b, const float* __restrict__ bhh_b,
    s16x8* __restrict__ whh, s16x8* __restrict__ wih, s16x8* __restrict__ wout,
    float* __restrict__ bias) {
  int bid = blockIdx.x, tid = threadIdx.x;
  if (bid < 256) {  // Whh: gid in [0, 65536)
    int gid = bid * 256 + tid;
    int l = gid & 63, kt = (gid >> 6) & 7, n = (gid >> 9) & 63, dir = gid >> 15;
    const float* src = dir ? Whh_b : Whh_f;
    int row = n * 16 + (l & 15), k0 = kt * 32 + ((l >> 4) << 3);
    s16x8 v;
#pragma unroll
    for (int e = 0; e < 8; ++e) v[e] = (short)f2bf(src[row * 256 + k0 + e]);
    whh[gid] = v;
  } else if (bid < 384) {  // Wih: gid in [0, 32768)
    int gid = (bid - 256) * 256 + tid;
    int l = gid & 63, kt = (gid >> 6) & 3, n = (gid >> 8) & 63, dir = gid >> 14;
    const float* src = dir ? Wih_b : Wih_f;
    int row = n * 16 + (l & 15), k0 = kt * 32 + ((l >> 4) << 3);
    s16x8 v;
#pragma unroll
    for (int e = 0; e < 8; ++e) {
      int k = k0 + e;
      v[e] = (k < 100) ? (short)f2bf(src[row * 100 + k]) : (short)0;
    }
    wih[gid] = v;
  } else if (bid < 392) {  // Wout: gid in [0, 2048)
    int gid = (bid - 384) * 256 + tid;
    int l = gid & 63, kt = (gid >> 6) & 7, n = (gid >> 9) & 1, dir = gid >> 10;
    int colt = n * 16 + (l & 15), k0 = kt * 32 + ((l >> 4) << 3);
    s16x8 v;
#pragma unroll
    for (int e = 0; e < 8; ++e)
      v[e] = (colt < 20) ? (short)f2bf(Wout[colt * 512 + dir * 256 + k0 + e]) : (short)0;
    wout[gid] = v;
  } else {  // bias: idx in [0, 2048)
    int idx = (bid - 392) * 256 + tid;
    if (idx < 2048) {
      int dir = idx >> 10, c = idx & 1023;
      bias[idx] = dir ? (bih_b[c] + bhh_b[c]) : (bih_f[c] + bhh_f[c]);
    }
  }
}

// ---------------------------------------------------------------------------
// K1: BiLSTM recurrence + fused emissions.
// grid = 16 blocks (dir = bx>>3, batch-tile = bx&7), 512 threads (8 waves).
// Wave w owns gate columns [w*128, (w+1)*128).
// ---------------------------------------------------------------------------
__global__ __launch_bounds__(512) void lstm_kernel(
    const int* __restrict__ sent, const float* __restrict__ emb,
    const s16x8* __restrict__ whh, const s16x8* __restrict__ wih,
    const s16x8* __restrict__ wout, const float* __restrict__ bias,
    float* __restrict__ em_out)  // [2][128][512][20]
{
  __shared__ unsigned short h_lds[16][264];   // bf16 h, row-major (pad to 264)
  __shared__ unsigned short x_lds[16][128];   // bf16 x (E=100, pad 128 w/ zeros)
  __shared__ unsigned short g_T[1024][24];    // bf16 gates, [col][row] (pad 24)

  const int tid = threadIdx.x;
  const int lid = tid & 63, w = tid >> 6;
  const int dir = blockIdx.x >> 3, bt = blockIdx.x & 7;
  const int r0 = bt * 16;

  const s16x8* whh_d = whh + dir * 32768;
  const s16x8* wih_d = wih + dir * 16384;
  const s16x8* wout_d = wout + dir * 1024;

  const int arow = lid & 15;          // A-frag / C-frag column-lane
  const int ak = (lid >> 4) << 3;     // A-frag k-offset within 32-k tile
  const int rb = (lid >> 4) * 2 * 2;  // C-frag row base = (lid>>4)*4

  // bias for this wave's 8 ntiles (constant across steps)
  float brg[8];
#pragma unroll
  for (int n = 0; n < 8; ++n) brg[n] = bias[dir * 1024 + w * 128 + n * 16 + arow];

  // zero h, x (incl. padding)
  for (int i = tid; i < 16 * 264; i += 512) ((unsigned short*)h_lds)[i] = 0;
  for (int i = tid; i < 16 * 128; i += 512) ((unsigned short*)x_lds)[i] = 0;

  // c state in registers: thread owns col j = tid>>1, rows rh..rh+8
  const int j_own = tid >> 1;
  const int rh_own = (tid & 1) * 8;
  float creg[8];
#pragma unroll
  for (int r = 0; r < 8; ++r) creg[r] = 0.f;

  __syncthreads();

  for (int t = 0; t < 512; ++t) {
    const int t_eff = dir ? (511 - t) : t;

    // ---- stage x(t): 400 threads, 16 rows x 25 float4 chunks ----
    if (tid < 400) {
      int row = tid / 25, cg = tid - row * 25;
      int sid = sent[(r0 + row) * 512 + t_eff];
      const float4 v = *(const float4*)&emb[sid * 100 + cg * 4];
      uint2 pk;
      pk.x = (unsigned)f2bf(v.x) | ((unsigned)f2bf(v.y) << 16);
      pk.y = (unsigned)f2bf(v.z) | ((unsigned)f2bf(v.w) << 16);
      *(uint2*)&x_lds[row][cg * 4] = pk;
    }
    __syncthreads();  // x ready; h(t-1) ready

    // ---- gate GEMM: [16 x 128cols] per wave, K = 256(h) + 128(x,pad) ----
    f32x4 acc[8];
#pragma unroll
    for (int n = 0; n < 8; ++n) {
      f32x4 a = {brg[n], brg[n], brg[n], brg[n]};
      acc[n] = a;
    }
#pragma unroll
    for (int kt = 0; kt < 8; ++kt) {
      s16x8 afrag = *(const s16x8*)&h_lds[arow][kt * 32 + ak];
#pragma unroll
      for (int n = 0; n < 8; ++n)
        acc[n] = MFMA16(afrag, whh_d[((w * 8 + n) * 8 + kt) * 64 + lid], acc[n]);
    }
#pragma unroll
    for (int kt = 0; kt < 4; ++kt) {
      s16x8 afrag = *(const s16x8*)&x_lds[arow][kt * 32 + ak];
#pragma unroll
      for (int n = 0; n < 8; ++n)
        acc[n] = MFMA16(afrag, wih_d[((w * 8 + n) * 4 + kt) * 64 + lid], acc[n]);
    }
    // store gates transposed ([col][row]) as bf16
#pragma unroll
    for (int n = 0; n < 8; ++n) {
      int col = w * 128 + n * 16 + arow;
      uint2 pk;
      pk.x = (unsigned)f2bf(acc[n][0]) | ((unsigned)f2bf(acc[n][1]) << 16);
      pk.y = (unsigned)f2bf(acc[n][2]) | ((unsigned)f2bf(acc[n][3]) << 16);
      *(uint2*)&g_T[col][rb] = pk;
    }
    __syncthreads();  // gates ready

    // ---- h/c update: thread owns (col j_own, rows rh_own..rh_own+8) ----
    {
      s16x8 gi = *(const s16x8*)&g_T[j_own][rh_own];
      s16x8 gf = *(const s16x8*)&g_T[256 + j_own][rh_own];
      s16x8 gg = *(const s16x8*)&g_T[512 + j_own][rh_own];
      s16x8 go = *(const s16x8*)&g_T[768 + j_own][rh_own];
      unsigned short hv[8];
#pragma unroll
      for (int r = 0; r < 8; ++r) {
        float xi = bf2f((unsigned short)gi[r]);
        float xf = bf2f((unsigned short)gf[r]);
        float xg = bf2f((unsigned short)gg[r]);
        float xo = bf2f((unsigned short)go[r]);
        float c = sigm(xf) * creg[r] + sigm(xi) * tanh_(xg);
        creg[r] = c;
        hv[r] = f2bf(sigm(xo) * tanh_(c));
      }
#pragma unroll
      for (int r = 0; r < 8; ++r) h_lds[rh_own + r][j_own] = hv[r];
    }
    __syncthreads();  // h(t) ready

    // ---- fused emissions: em = h @ Wout_slice^T (waves 0,1 only) ----
    if (w < 2) {
      f32x4 e = {0.f, 0.f, 0.f, 0.f};
#pragma unroll
      for (int kt = 0; kt < 8; ++kt) {
        s16x8 afrag = *(const s16x8*)&h_lds[arow][kt * 32 + ak];
        e = MFMA16(afrag, wout_d[(w * 8 + kt) * 64 + lid], e);
      }
      int col = w * 16 + arow;
      if (col < 20) {
        int base = ((dir * 128 + r0 + rb) * 512 + t_eff) * 20 + col;
#pragma unroll
        for (int r = 0; r < 4; ++r) em_out[base + r * 10240] = e[r];
      }
    }
  }
}

// ---------------------------------------------------------------------------
// K2: CRF gold score + forward algorithm. 128 blocks x 64 threads (1 wave).
// mask is int32 (one int per position).
// ---------------------------------------------------------------------------
__global__ __launch_bounds__(64) void crf_kernel(
    const float* __restrict__ emf, const float* __restrict__ embk,
    const int* __restrict__ tags, const int* __restrict__ maski,
    const float* __restrict__ bout, const float* __restrict__ trans,
    const float* __restrict__ start_t, const float* __restrict__ end_t,
    float* __restrict__ partial) {
  __shared__ float tr[400];
  const int b = blockIdx.x, tid = threadIdx.x;
  for (int i = tid; i < 400; i += 64) tr[i] = trans[i];
  __syncthreads();

  const int tp = tid;
  const bool act = tp < 20;
  float eT[20];
  if (act) {
#pragma unroll
    for (int t2 = 0; t2 < 20; ++t2) eT[t2] = __expf(tr[t2 * 20 + tp]);
  }
  const float* ef = emf + (size_t)b * 10240;
  const float* eb = embk + (size_t)b * 10240;
  const float bo = act ? bout[tp] : 0.f;

  float a = act ? (start_t[tp] + ef[tp] + eb[tp] + bo) : -1e30f;

  float efn = 0.f, ebn = 0.f;
  if (act) { efn = ef[20 + tp]; ebn = eb[20 + tp]; }

  for (int l = 1; l < 512; ++l) {
    float e_cur = efn + ebn + bo;
    if (act && l + 1 < 512) { efn = ef[(l + 1) * 20 + tp]; ebn = eb[(l + 1) * 20 + tp]; }
    float m = a;
#pragma unroll
    for (int o = 16; o > 0; o >>= 1) m = fmaxf(m, __shfl_xor(m, o, 32));
    float p = __expf(a - m);
    float s = 0.f;
#pragma unroll
    for (int t2 = 0; t2 < 20; ++t2) s += __shfl(p, t2, 32) * eT[t2];
    float anew = m + __logf(s) + e_cur;
    int mk = maski[b * 512 + l];
    if (act && mk) a = anew;
  }
  // logZ = logsumexp(a + end)
  float v = act ? (a + end_t[tp]) : -1e30f;
  float m2 = v;
#pragma unroll
  for (int o = 16; o > 0; o >>= 1) m2 = fmaxf(m2, __shfl_xor(m2, o, 32));
  float s2 = __expf(v - m2);
#pragma unroll
  for (int o = 16; o > 0; o >>= 1) s2 += __shfl_xor(s2, o, 32);
  float logZ = m2 + __logf(s2);

  // gold path score + mask count (all 64 lanes)
  const int* tg = tags + b * 512;
  float sc = 0.f;
  int cnt = 0;
  for (int l = tid; l < 512; l += 64) {
    int mk = maski[b * 512 + l];
    cnt += mk ? 1 : 0;
    if (l >= 1 && mk) {
      int cur = tg[l], prev = tg[l - 1];
      sc += tr[prev * 20 + cur] + ef[l * 20 + cur] + eb[l * 20 + cur] + bout[cur];
    }
  }
#pragma unroll
  for (int o = 32; o > 0; o >>= 1) {
    sc += __shfl_xor(sc, o, 64);
    cnt += __shfl_xor(cnt, o, 64);
  }
  if (tid == 0) {
    int t0 = tg[0];
    sc += start_t[t0] + ef[t0] + eb[t0] + bout[t0];
    sc += end_t[tg[cnt - 1]];
    partial[b] = sc - logZ;
  }
}

// ---------------------------------------------------------------------------
// K3: final reduction -> |sum|, f32 output.
// ---------------------------------------------------------------------------
__global__ __launch_bounds__(64) void final_kernel(const float* __restrict__ partial,
                                                   float* __restrict__ out) {
  int tid = threadIdx.x;
  float s = partial[tid] + partial[tid + 64];
#pragma unroll
  for (int o = 32; o > 0; o >>= 1) s += __shfl_xor(s, o, 64);
  if (tid == 0) out[0] = fabsf(s);
}

// ---------------------------------------------------------------------------
extern "C" void kernel_launch(void* const* d_in, const int* in_sizes, int n_in,
                              void* d_out, int out_size, void* d_ws, size_t ws_size,
                              hipStream_t stream) {
  const int* sent = (const int*)d_in[0];
  const int* tags = (const int*)d_in[1];
  const int* maski = (const int*)d_in[2];  // bool -> int32 per harness contract
  const float* emb = (const float*)d_in[3];
  const float* Wih_f = (const float*)d_in[4];
  const float* Whh_f = (const float*)d_in[5];
  const float* bih_f = (const float*)d_in[6];
  const float* bhh_f = (const float*)d_in[7];
  const float* Wih_b = (const float*)d_in[8];
  const float* Whh_b = (const float*)d_in[9];
  const float* bih_b = (const float*)d_in[10];
  const float* bhh_b = (const float*)d_in[11];
  const float* Wout = (const float*)d_in[12];
  const float* bout = (const float*)d_in[13];
  const float* trans = (const float*)d_in[14];
  const float* start_t = (const float*)d_in[15];
  const float* end_t = (const float*)d_in[16];

  char* ws = (char*)d_ws;
  float* em_base = (float*)ws;                       // [2][128][512][20] f32
  float* em_f = em_base;
  float* em_b = em_base + 128 * 512 * 20;
  s16x8* whh_sw = (s16x8*)(ws + 10485760);
  s16x8* wih_sw = (s16x8*)(ws + 11534336);
  s16x8* wout_sw = (s16x8*)(ws + 12058624);
  float* bias_d = (float*)(ws + 12091392);
  float* partial = (float*)(ws + 12099584);

  prep_kernel<<<400, 256, 0, stream>>>(Whh_f, Whh_b, Wih_f, Wih_b, Wout,
                                       bih_f, bhh_f, bih_b, bhh_b,
                                       whh_sw, wih_sw, wout_sw, bias_d);
  lstm_kernel<<<16, 512, 0, stream>>>(sent, emb, whh_sw, wih_sw, wout_sw,
                                      bias_d, em_base);
  crf_kernel<<<128, 64, 0, stream>>>(em_f, em_b, tags, maski, bout, trans,
                                     start_t, end_t, partial);
  final_kernel<<<1, 64, 0, stream>>>(partial, (float*)d_out);
}